// Round 1
// baseline (1214.749 us; speedup 1.0000x reference)
//
#include <hip/hip_runtime.h>

#define TT 8192
#define DD 1024
#define HH 2816
#define NE 8
#define BK 32
#define LDK 40   // LDS leading dim: 32 + 8 pad -> 2-way bank aliasing only (free)

typedef unsigned short u16;
typedef __attribute__((ext_vector_type(8))) short short8;
typedef __attribute__((ext_vector_type(4))) float floatx4;

__device__ __forceinline__ u16 f2b(float f) {
  unsigned u = __float_as_uint(f);
  unsigned r = u + 0x7fffu + ((u >> 16) & 1u);
  return (u16)(r >> 16);
}

// ---------------- fp32 -> bf16 conversion (grid-stride-free, exact-size) ----------------
__global__ void cvt_kernel(const float* __restrict__ src, u16* __restrict__ dst, int n4) {
  int i = blockIdx.x * blockDim.x + threadIdx.x;
  if (i >= n4) return;
  float4 v = ((const float4*)src)[i];
  ushort4 o;
  o.x = f2b(v.x); o.y = f2b(v.y); o.z = f2b(v.z); o.w = f2b(v.w);
  ((ushort4*)dst)[i] = o;
}

// ---------------- gate: logits -> softmax -> top2 -> slot lists ----------------
__global__ void gate_kernel(const float* __restrict__ x, const float* __restrict__ gw,
                            int* __restrict__ cnt, int* __restrict__ slots,
                            float* __restrict__ wgt) {
  int t = blockIdx.x;
  int l = threadIdx.x;  // 64 threads = 1 wave
  const float4* xr = (const float4*)(x + (size_t)t * DD);
  float acc[NE];
#pragma unroll
  for (int e = 0; e < NE; ++e) acc[e] = 0.f;
#pragma unroll
  for (int c = 0; c < 4; ++c) {
    float4 xv = xr[l + c * 64];
#pragma unroll
    for (int e = 0; e < NE; ++e) {
      float4 g = ((const float4*)(gw + e * DD))[l + c * 64];
      acc[e] += xv.x * g.x + xv.y * g.y + xv.z * g.z + xv.w * g.w;
    }
  }
#pragma unroll
  for (int e = 0; e < NE; ++e)
    for (int off = 32; off > 0; off >>= 1)
      acc[e] += __shfl_xor(acc[e], off);
  if (l == 0) {
    float m = acc[0];
#pragma unroll
    for (int e = 1; e < NE; ++e) m = fmaxf(m, acc[e]);
    float p[NE]; float s = 0.f;
#pragma unroll
    for (int e = 0; e < NE; ++e) { p[e] = __expf(acc[e] - m); s += p[e]; }
#pragma unroll
    for (int e = 0; e < NE; ++e) p[e] /= s;
    int i1 = 0;
    for (int e = 1; e < NE; ++e) if (p[e] > p[i1]) i1 = e;       // first-index tiebreak
    int i2 = (i1 == 0) ? 1 : 0;
    for (int e = 0; e < NE; ++e) if (e != i1 && p[e] > p[i2]) i2 = e;
    float d = p[i1] + p[i2] + 1e-20f;
    float w1v = p[i1] / d, w2v = p[i2] / d;
    int p1 = atomicAdd(&cnt[i1], 1);
    slots[i1 * TT + p1] = t; wgt[i1 * TT + p1] = w1v;
    int p2 = atomicAdd(&cnt[i2], 1);
    slots[i2 * TT + p2] = t; wgt[i2 * TT + p2] = w2v;
    // shared expert = expert 8, identity list, weight 1
    slots[8 * TT + t] = t; wgt[8 * TT + t] = 1.0f;
  }
}

__global__ void scan_kernel(int* __restrict__ cnt, int* __restrict__ basep) {
  cnt[8] = TT;
  int s = 0;
  for (int e = 0; e < 9; ++e) { basep[e] = s; s += cnt[e]; }
}

// ---------------- FFN stage 1: h = silu(x@w1^T) * (x@w3^T), gathered rows ----------------
__global__ __launch_bounds__(256, 2) void ffn1_kernel(
    const u16* __restrict__ xb, const u16* __restrict__ w1b, const u16* __restrict__ w3b,
    const int* __restrict__ cnt, const int* __restrict__ basep,
    const int* __restrict__ slots, u16* __restrict__ hbuf) {
  int e = blockIdx.z;
  int ne = cnt[e];
  int rt = blockIdx.y;
  if (rt * 128 >= ne) return;
  int ct = blockIdx.x;
  int c0 = ct * 128;
  int tid = threadIdx.x;

  __shared__ u16 sA[128 * LDK];
  __shared__ u16 sB1[128 * LDK];
  __shared__ u16 sB3[128 * LDK];
  __shared__ int s_tok[128];

  if (tid < 128) {
    int row = rt * 128 + tid;
    s_tok[tid] = (row < ne) ? slots[e * TT + row] : slots[e * TT];
  }
  __syncthreads();

  const u16* w1e = w1b + (size_t)e * HH * DD;
  const u16* w3e = w3b + (size_t)e * HH * DD;

  int wv = tid >> 6, l = tid & 63;
  int wm = wv & 1, wn = wv >> 1;
  int lo = l & 15, hi = l >> 4;

  floatx4 acc1[4][4], acc3[4][4];
#pragma unroll
  for (int i = 0; i < 4; ++i)
#pragma unroll
    for (int j = 0; j < 4; ++j) {
      acc1[i][j] = (floatx4){0.f, 0.f, 0.f, 0.f};
      acc3[i][j] = (floatx4){0.f, 0.f, 0.f, 0.f};
    }

  int r0 = tid >> 2, cc0 = (tid & 3) * 8;
  int r1 = r0 + 64;

  for (int kt = 0; kt < DD / BK; ++kt) {
    int k0 = kt * BK;
    uint4 a0 = *(const uint4*)(xb + (size_t)s_tok[r0] * DD + k0 + cc0);
    uint4 a1 = *(const uint4*)(xb + (size_t)s_tok[r1] * DD + k0 + cc0);
    uint4 v10 = *(const uint4*)(w1e + (size_t)(c0 + r0) * DD + k0 + cc0);
    uint4 v11 = *(const uint4*)(w1e + (size_t)(c0 + r1) * DD + k0 + cc0);
    uint4 v30 = *(const uint4*)(w3e + (size_t)(c0 + r0) * DD + k0 + cc0);
    uint4 v31 = *(const uint4*)(w3e + (size_t)(c0 + r1) * DD + k0 + cc0);
    *(uint4*)(sA + r0 * LDK + cc0) = a0;
    *(uint4*)(sA + r1 * LDK + cc0) = a1;
    *(uint4*)(sB1 + r0 * LDK + cc0) = v10;
    *(uint4*)(sB1 + r1 * LDK + cc0) = v11;
    *(uint4*)(sB3 + r0 * LDK + cc0) = v30;
    *(uint4*)(sB3 + r1 * LDK + cc0) = v31;
    __syncthreads();

    short8 af[4], b1f[4], b3f[4];
    int koff = hi * 8;
#pragma unroll
    for (int mi = 0; mi < 4; ++mi)
      af[mi] = *(const short8*)(sA + (wm * 64 + mi * 16 + lo) * LDK + koff);
#pragma unroll
    for (int ni = 0; ni < 4; ++ni) {
      b1f[ni] = *(const short8*)(sB1 + (wn * 64 + ni * 16 + lo) * LDK + koff);
      b3f[ni] = *(const short8*)(sB3 + (wn * 64 + ni * 16 + lo) * LDK + koff);
    }
#pragma unroll
    for (int mi = 0; mi < 4; ++mi)
#pragma unroll
      for (int ni = 0; ni < 4; ++ni) {
        acc1[mi][ni] = __builtin_amdgcn_mfma_f32_16x16x32_bf16(af[mi], b1f[ni], acc1[mi][ni], 0, 0, 0);
        acc3[mi][ni] = __builtin_amdgcn_mfma_f32_16x16x32_bf16(af[mi], b3f[ni], acc3[mi][ni], 0, 0, 0);
      }
    __syncthreads();
  }

  int hb = basep[e];
#pragma unroll
  for (int mi = 0; mi < 4; ++mi) {
#pragma unroll
    for (int ni = 0; ni < 4; ++ni) {
#pragma unroll
      for (int r = 0; r < 4; ++r) {
        int row = wm * 64 + mi * 16 + hi * 4 + r;
        int gr = rt * 128 + row;
        if (gr < ne) {
          int col = c0 + wn * 64 + ni * 16 + lo;
          float v1 = acc1[mi][ni][r], v3 = acc3[mi][ni][r];
          float h = v1 / (1.f + __expf(-v1)) * v3;
          hbuf[(size_t)(hb + gr) * HH + col] = f2b(h);
        }
      }
    }
  }
}

// ---------------- FFN stage 2: out[tok] += w_slot * (h @ w2^T) ----------------
__global__ __launch_bounds__(256, 2) void ffn2_kernel(
    const u16* __restrict__ hbuf, const u16* __restrict__ w2b,
    const int* __restrict__ cnt, const int* __restrict__ basep,
    const int* __restrict__ slots, const float* __restrict__ wgt,
    float* __restrict__ out) {
  int e = blockIdx.z;
  int ne = cnt[e];
  int rt = blockIdx.y;
  if (rt * 128 >= ne) return;
  int ct = blockIdx.x;
  int c0 = ct * 128;
  int tid = threadIdx.x;

  __shared__ u16 sA[128 * LDK];
  __shared__ u16 sB[128 * LDK];
  __shared__ int s_tok[128];
  __shared__ float s_w[128];

  int hb = basep[e];
  if (tid < 128) {
    int row = rt * 128 + tid;
    if (row < ne) {
      s_tok[tid] = slots[e * TT + row];
      s_w[tid] = wgt[e * TT + row];
    } else {
      s_tok[tid] = 0; s_w[tid] = 0.f;
    }
  }
  __syncthreads();

  const u16* Ae = hbuf + (size_t)(hb + rt * 128) * HH;
  const u16* w2e = w2b + (size_t)e * DD * HH;

  int wv = tid >> 6, l = tid & 63;
  int wm = wv & 1, wn = wv >> 1;
  int lo = l & 15, hi = l >> 4;

  floatx4 acc[4][4];
#pragma unroll
  for (int i = 0; i < 4; ++i)
#pragma unroll
    for (int j = 0; j < 4; ++j) acc[i][j] = (floatx4){0.f, 0.f, 0.f, 0.f};

  int r0 = tid >> 2, cc0 = (tid & 3) * 8;
  int r1 = r0 + 64;

  for (int kt = 0; kt < HH / BK; ++kt) {
    int k0 = kt * BK;
    uint4 a0 = *(const uint4*)(Ae + (size_t)r0 * HH + k0 + cc0);
    uint4 a1 = *(const uint4*)(Ae + (size_t)r1 * HH + k0 + cc0);
    uint4 b0 = *(const uint4*)(w2e + (size_t)(c0 + r0) * HH + k0 + cc0);
    uint4 b1 = *(const uint4*)(w2e + (size_t)(c0 + r1) * HH + k0 + cc0);
    *(uint4*)(sA + r0 * LDK + cc0) = a0;
    *(uint4*)(sA + r1 * LDK + cc0) = a1;
    *(uint4*)(sB + r0 * LDK + cc0) = b0;
    *(uint4*)(sB + r1 * LDK + cc0) = b1;
    __syncthreads();

    short8 af[4], bf[4];
    int koff = hi * 8;
#pragma unroll
    for (int mi = 0; mi < 4; ++mi)
      af[mi] = *(const short8*)(sA + (wm * 64 + mi * 16 + lo) * LDK + koff);
#pragma unroll
    for (int ni = 0; ni < 4; ++ni)
      bf[ni] = *(const short8*)(sB + (wn * 64 + ni * 16 + lo) * LDK + koff);
#pragma unroll
    for (int mi = 0; mi < 4; ++mi)
#pragma unroll
      for (int ni = 0; ni < 4; ++ni)
        acc[mi][ni] = __builtin_amdgcn_mfma_f32_16x16x32_bf16(af[mi], bf[ni], acc[mi][ni], 0, 0, 0);
    __syncthreads();
  }

#pragma unroll
  for (int mi = 0; mi < 4; ++mi) {
#pragma unroll
    for (int ni = 0; ni < 4; ++ni) {
#pragma unroll
      for (int r = 0; r < 4; ++r) {
        int row = wm * 64 + mi * 16 + hi * 4 + r;
        int gr = rt * 128 + row;
        if (gr < ne) {
          int col = c0 + wn * 64 + ni * 16 + lo;
          atomicAdd(out + (size_t)s_tok[row] * DD + col, acc[mi][ni][r] * s_w[row]);
        }
      }
    }
  }
}

extern "C" void kernel_launch(void* const* d_in, const int* in_sizes, int n_in,
                              void* d_out, int out_size, void* d_ws, size_t ws_size,
                              hipStream_t stream) {
  const float* x   = (const float*)d_in[0];
  const float* gw  = (const float*)d_in[1];
  const float* w1  = (const float*)d_in[2];
  const float* w2  = (const float*)d_in[3];
  const float* w3  = (const float*)d_in[4];
  const float* sw1 = (const float*)d_in[5];
  const float* sw2 = (const float*)d_in[6];
  const float* sw3 = (const float*)d_in[7];
  float* out = (float*)d_out;

  char* ws = (char*)d_ws;
  size_t off = 0;
  int* cnt = (int*)(ws + off);    off += 64;
  int* basep = (int*)(ws + off);  off += 64;
  int* slots = (int*)(ws + off);  off += (size_t)9 * TT * 4;
  float* wgt = (float*)(ws + off); off += (size_t)9 * TT * 4;
  u16* xb  = (u16*)(ws + off);    off += (size_t)TT * DD * 2;
  u16* w1b = (u16*)(ws + off);    off += (size_t)9 * HH * DD * 2;
  u16* w3b = (u16*)(ws + off);    off += (size_t)9 * HH * DD * 2;
  u16* w2b = (u16*)(ws + off);    off += (size_t)9 * DD * HH * 2;
  u16* hbuf = (u16*)(ws + off);   off += (size_t)(3 * TT) * HH * 2;
  // total ws use ~311.5 MB

  hipMemsetAsync(cnt, 0, 64, stream);
  hipMemsetAsync(out, 0, (size_t)TT * DD * 4, stream);

  const int b = 256;
  int nx = TT * DD / 4;          // 2,097,152
  int nw = 8 * HH * DD / 4;      // 5,767,168
  int ns = HH * DD / 4;          // 720,896
  cvt_kernel<<<(nx + b - 1) / b, b, 0, stream>>>(x, xb, nx);
  cvt_kernel<<<(nw + b - 1) / b, b, 0, stream>>>(w1, w1b, nw);
  cvt_kernel<<<(ns + b - 1) / b, b, 0, stream>>>(sw1, w1b + (size_t)8 * HH * DD, ns);
  cvt_kernel<<<(nw + b - 1) / b, b, 0, stream>>>(w3, w3b, nw);
  cvt_kernel<<<(ns + b - 1) / b, b, 0, stream>>>(sw3, w3b + (size_t)8 * HH * DD, ns);
  cvt_kernel<<<(nw + b - 1) / b, b, 0, stream>>>(w2, w2b, nw);
  cvt_kernel<<<(ns + b - 1) / b, b, 0, stream>>>(sw2, w2b + (size_t)8 * DD * HH, ns);

  gate_kernel<<<TT, 64, 0, stream>>>(x, gw, cnt, slots, wgt);
  scan_kernel<<<1, 1, 0, stream>>>(cnt, basep);

  ffn1_kernel<<<dim3(HH / 128, 64, 9), 256, 0, stream>>>(xb, w1b, w3b, cnt, basep, slots, hbuf);
  ffn2_kernel<<<dim3(DD / 128, 64, 9), 256, 0, stream>>>(hbuf, w2b, cnt, basep, slots, wgt, out);
}

// Round 2
// 1130.227 us; speedup vs baseline: 1.0748x; 1.0748x over previous
//
#include <hip/hip_runtime.h>

#define TT 8192
#define DD 1024
#define HH 2816
#define NE 8

typedef unsigned short u16;
typedef unsigned int u32;
typedef __attribute__((ext_vector_type(8))) short short8;
typedef __attribute__((ext_vector_type(4))) float floatx4;

__device__ __forceinline__ u16 f2b(float f) {
  unsigned u = __float_as_uint(f);
  unsigned r = u + 0x7fffu + ((u >> 16) & 1u);
  return (u16)(r >> 16);
}
__device__ __forceinline__ float b2f(u16 v) { return __uint_as_float(((u32)v) << 16); }

// async global->LDS, 16B per lane; LDS dest = wave-uniform base + lane*16
__device__ __forceinline__ void gl16(const u16* g, u16* l) {
  __builtin_amdgcn_global_load_lds(
      (const __attribute__((address_space(1))) u32*)g,
      (__attribute__((address_space(3))) u32*)l, 16, 0, 0);
}

// ---------------- fp32 -> bf16 conversion ----------------
__global__ void cvt_kernel(const float* __restrict__ src, u16* __restrict__ dst, int n4) {
  int i = blockIdx.x * blockDim.x + threadIdx.x;
  if (i >= n4) return;
  float4 v = ((const float4*)src)[i];
  ushort4 o;
  o.x = f2b(v.x); o.y = f2b(v.y); o.z = f2b(v.z); o.w = f2b(v.w);
  ((ushort4*)dst)[i] = o;
}

// ---------------- gate ----------------
__global__ void gate_kernel(const float* __restrict__ x, const float* __restrict__ gw,
                            int* __restrict__ cnt, int* __restrict__ slots,
                            int* __restrict__ tok2slot, float* __restrict__ tok2wgt) {
  int t = blockIdx.x;
  int l = threadIdx.x;  // 64 threads = 1 wave
  const float4* xr = (const float4*)(x + (size_t)t * DD);
  float acc[NE];
#pragma unroll
  for (int e = 0; e < NE; ++e) acc[e] = 0.f;
#pragma unroll
  for (int c = 0; c < 4; ++c) {
    float4 xv = xr[l + c * 64];
#pragma unroll
    for (int e = 0; e < NE; ++e) {
      float4 g = ((const float4*)(gw + e * DD))[l + c * 64];
      acc[e] += xv.x * g.x + xv.y * g.y + xv.z * g.z + xv.w * g.w;
    }
  }
#pragma unroll
  for (int e = 0; e < NE; ++e)
    for (int off = 32; off > 0; off >>= 1)
      acc[e] += __shfl_xor(acc[e], off);
  if (l == 0) {
    float m = acc[0];
#pragma unroll
    for (int e = 1; e < NE; ++e) m = fmaxf(m, acc[e]);
    float p[NE]; float s = 0.f;
#pragma unroll
    for (int e = 0; e < NE; ++e) { p[e] = __expf(acc[e] - m); s += p[e]; }
#pragma unroll
    for (int e = 0; e < NE; ++e) p[e] /= s;
    int i1 = 0;
    for (int e = 1; e < NE; ++e) if (p[e] > p[i1]) i1 = e;
    int i2 = (i1 == 0) ? 1 : 0;
    for (int e = 0; e < NE; ++e) if (e != i1 && p[e] > p[i2]) i2 = e;
    float d = p[i1] + p[i2] + 1e-20f;
    float wa = p[i1] / d, wb = p[i2] / d;
    int p1 = atomicAdd(&cnt[i1], 1);
    slots[i1 * TT + p1] = t;
    int p2 = atomicAdd(&cnt[i2], 1);
    slots[i2 * TT + p2] = t;
    tok2slot[2 * t] = i1 * TT + p1;  tok2wgt[2 * t] = wa;
    tok2slot[2 * t + 1] = i2 * TT + p2;  tok2wgt[2 * t + 1] = wb;
  }
}

__global__ void scan_kernel(int* __restrict__ cnt, int* __restrict__ basep) {
  cnt[8] = TT;
  int s = 0;
  for (int e = 0; e < 9; ++e) { basep[e] = s; s += cnt[e]; }
}

// ---------------- gather x rows (fp32 -> bf16, compacted per expert) ----------------
__global__ void gatherx_kernel(const float* __restrict__ x, const int* __restrict__ cnt,
                               const int* __restrict__ basep, const int* __restrict__ slots,
                               u16* __restrict__ xg) {
  int e = blockIdx.y;
  int p = blockIdx.x * 2 + (threadIdx.x >> 7);
  int ne = (e < 8) ? cnt[e] : TT;
  if (p >= ne) return;
  int tok = (e < 8) ? slots[e * TT + p] : p;
  int dst = basep[e] + p;
  int lane = threadIdx.x & 127;
  const float4* src = (const float4*)(x + (size_t)tok * DD) + lane * 2;
  float4 v0 = src[0], v1 = src[1];
  ushort4 o0, o1;
  o0.x = f2b(v0.x); o0.y = f2b(v0.y); o0.z = f2b(v0.z); o0.w = f2b(v0.w);
  o1.x = f2b(v1.x); o1.y = f2b(v1.y); o1.z = f2b(v1.z); o1.w = f2b(v1.w);
  ushort4* dp = (ushort4*)(xg + (size_t)dst * DD) + lane * 2;
  dp[0] = o0; dp[1] = o1;
}

// ---------------- FFN stage 1: h = silu(xg@w1^T) * (xg@w3^T) ----------------
__global__ __launch_bounds__(256, 2) void ffn1_kernel(
    const u16* __restrict__ xg, const u16* __restrict__ w1b, const u16* __restrict__ w3b,
    const int* __restrict__ cnt, const int* __restrict__ basep, u16* __restrict__ hbuf) {
  int e = blockIdx.z;
  int ne = (e < 8) ? cnt[e] : TT;
  int rt = blockIdx.y;
  if (rt * 128 >= ne) return;
  int c0 = blockIdx.x * 128;
  int tid = threadIdx.x;
  int wv = tid >> 6, l = tid & 63;

  __shared__ u16 sA[128 * 32];
  __shared__ u16 sB1[128 * 32];
  __shared__ u16 sB3[128 * 32];

  int row0 = basep[e] + rt * 128;
  const u16* Ab = xg + (size_t)row0 * DD;
  const u16* B1b = w1b + (size_t)e * HH * DD + (size_t)c0 * DD;
  const u16* B3b = w3b + (size_t)e * HH * DD + (size_t)c0 * DD;

  // staging: granule g (16B) -> LDS slot g; source col XOR-swizzled by row
  int g0 = wv * 64 + l, g1 = 256 + g0;
  int r0 = g0 >> 2, cs0 = ((g0 & 3) ^ ((r0 >> 1) & 3)) * 8;
  int r1 = g1 >> 2, cs1 = ((g1 & 3) ^ ((r1 >> 1) & 3)) * 8;
  const u16* pA0 = Ab + (size_t)r0 * DD + cs0;
  const u16* pA1 = Ab + (size_t)r1 * DD + cs1;
  const u16* pB10 = B1b + (size_t)r0 * DD + cs0;
  const u16* pB11 = B1b + (size_t)r1 * DD + cs1;
  const u16* pB30 = B3b + (size_t)r0 * DD + cs0;
  const u16* pB31 = B3b + (size_t)r1 * DD + cs1;
  u16* dA0 = sA + wv * 512;  u16* dA1 = sA + 2048 + wv * 512;
  u16* dB10 = sB1 + wv * 512; u16* dB11 = sB1 + 2048 + wv * 512;
  u16* dB30 = sB3 + wv * 512; u16* dB31 = sB3 + 2048 + wv * 512;

  int wm = wv & 1, wn = wv >> 1;
  int lo = l & 15, hi = l >> 4;
  int sw8 = (hi ^ ((lo >> 1) & 3)) * 8;
  int aoff = (wm * 64 + lo) * 32 + sw8;
  int boff = (wn * 64 + lo) * 32 + sw8;

  floatx4 acc1[4][4], acc3[4][4];
#pragma unroll
  for (int i = 0; i < 4; ++i)
#pragma unroll
    for (int j = 0; j < 4; ++j) {
      acc1[i][j] = (floatx4){0.f, 0.f, 0.f, 0.f};
      acc3[i][j] = (floatx4){0.f, 0.f, 0.f, 0.f};
    }

  for (int kt = 0; kt < DD / 32; ++kt) {
    gl16(pA0, dA0);  gl16(pA1, dA1);
    gl16(pB10, dB10); gl16(pB11, dB11);
    gl16(pB30, dB30); gl16(pB31, dB31);
    pA0 += 32; pA1 += 32; pB10 += 32; pB11 += 32; pB30 += 32; pB31 += 32;
    __syncthreads();

    short8 af[4], b1f[4], b3f[4];
#pragma unroll
    for (int mi = 0; mi < 4; ++mi)
      af[mi] = *(const short8*)(sA + aoff + mi * 512);
#pragma unroll
    for (int ni = 0; ni < 4; ++ni) {
      b1f[ni] = *(const short8*)(sB1 + boff + ni * 512);
      b3f[ni] = *(const short8*)(sB3 + boff + ni * 512);
    }
#pragma unroll
    for (int mi = 0; mi < 4; ++mi)
#pragma unroll
      for (int ni = 0; ni < 4; ++ni) {
        acc1[mi][ni] = __builtin_amdgcn_mfma_f32_16x16x32_bf16(af[mi], b1f[ni], acc1[mi][ni], 0, 0, 0);
        acc3[mi][ni] = __builtin_amdgcn_mfma_f32_16x16x32_bf16(af[mi], b3f[ni], acc3[mi][ni], 0, 0, 0);
      }
    __syncthreads();
  }

#pragma unroll
  for (int mi = 0; mi < 4; ++mi)
#pragma unroll
    for (int ni = 0; ni < 4; ++ni)
#pragma unroll
      for (int r = 0; r < 4; ++r) {
        int row = wm * 64 + mi * 16 + hi * 4 + r;
        if (rt * 128 + row < ne) {
          int col = c0 + wn * 64 + ni * 16 + lo;
          float v1 = acc1[mi][ni][r], v3 = acc3[mi][ni][r];
          float h = v1 / (1.f + __expf(-v1)) * v3;
          hbuf[(size_t)(row0 + row) * HH + col] = f2b(h);
        }
      }
}

// ---------------- FFN stage 2: y = h @ w2^T (unweighted, bf16) ----------------
__global__ __launch_bounds__(256, 3) void ffn2_kernel(
    const u16* __restrict__ hbuf, const u16* __restrict__ w2b,
    const int* __restrict__ cnt, const int* __restrict__ basep, u16* __restrict__ ybuf) {
  int e = blockIdx.z;
  int ne = (e < 8) ? cnt[e] : TT;
  int rt = blockIdx.y;
  if (rt * 128 >= ne) return;
  int c0 = blockIdx.x * 128;
  int tid = threadIdx.x;
  int wv = tid >> 6, l = tid & 63;

  __shared__ u16 sA[128 * 32];
  __shared__ u16 sB[128 * 32];

  int row0 = basep[e] + rt * 128;
  const u16* Ab = hbuf + (size_t)row0 * HH;
  const u16* Bb = w2b + (size_t)e * DD * HH + (size_t)c0 * HH;

  int g0 = wv * 64 + l, g1 = 256 + g0;
  int r0 = g0 >> 2, cs0 = ((g0 & 3) ^ ((r0 >> 1) & 3)) * 8;
  int r1 = g1 >> 2, cs1 = ((g1 & 3) ^ ((r1 >> 1) & 3)) * 8;
  const u16* pA0 = Ab + (size_t)r0 * HH + cs0;
  const u16* pA1 = Ab + (size_t)r1 * HH + cs1;
  const u16* pB0 = Bb + (size_t)r0 * HH + cs0;
  const u16* pB1 = Bb + (size_t)r1 * HH + cs1;
  u16* dA0 = sA + wv * 512;  u16* dA1 = sA + 2048 + wv * 512;
  u16* dB0 = sB + wv * 512;  u16* dB1 = sB + 2048 + wv * 512;

  int wm = wv & 1, wn = wv >> 1;
  int lo = l & 15, hi = l >> 4;
  int sw8 = (hi ^ ((lo >> 1) & 3)) * 8;
  int aoff = (wm * 64 + lo) * 32 + sw8;
  int boff = (wn * 64 + lo) * 32 + sw8;

  floatx4 acc[4][4];
#pragma unroll
  for (int i = 0; i < 4; ++i)
#pragma unroll
    for (int j = 0; j < 4; ++j) acc[i][j] = (floatx4){0.f, 0.f, 0.f, 0.f};

  for (int kt = 0; kt < HH / 32; ++kt) {
    gl16(pA0, dA0); gl16(pA1, dA1);
    gl16(pB0, dB0); gl16(pB1, dB1);
    pA0 += 32; pA1 += 32; pB0 += 32; pB1 += 32;
    __syncthreads();

    short8 af[4], bf[4];
#pragma unroll
    for (int mi = 0; mi < 4; ++mi)
      af[mi] = *(const short8*)(sA + aoff + mi * 512);
#pragma unroll
    for (int ni = 0; ni < 4; ++ni)
      bf[ni] = *(const short8*)(sB + boff + ni * 512);
#pragma unroll
    for (int mi = 0; mi < 4; ++mi)
#pragma unroll
      for (int ni = 0; ni < 4; ++ni)
        acc[mi][ni] = __builtin_amdgcn_mfma_f32_16x16x32_bf16(af[mi], bf[ni], acc[mi][ni], 0, 0, 0);
    __syncthreads();
  }

#pragma unroll
  for (int mi = 0; mi < 4; ++mi)
#pragma unroll
    for (int ni = 0; ni < 4; ++ni)
#pragma unroll
      for (int r = 0; r < 4; ++r) {
        int row = wm * 64 + mi * 16 + hi * 4 + r;
        if (rt * 128 + row < ne) {
          int col = c0 + wn * 64 + ni * 16 + lo;
          ybuf[(size_t)(row0 + row) * DD + col] = f2b(acc[mi][ni][r]);
        }
      }
}

// ---------------- combine: out[t] = w0*y[s0] + w1*y[s1] + y[shared] ----------------
__global__ void combine_kernel(const u16* __restrict__ ybuf, const int* __restrict__ tok2slot,
                               const float* __restrict__ tok2wgt, const int* __restrict__ basep,
                               float* __restrict__ out) {
  int idx = blockIdx.x * 256 + threadIdx.x;  // TT*DD/8 threads
  int t = idx >> 7;
  int c = (idx & 127) * 8;
  int e0 = tok2slot[2 * t], e1 = tok2slot[2 * t + 1];
  float w0 = tok2wgt[2 * t], w1 = tok2wgt[2 * t + 1];
  int rr0 = basep[e0 >> 13] + (e0 & 8191);
  int rr1 = basep[e1 >> 13] + (e1 & 8191);
  int rs = 2 * TT + t;
  const ushort4* y0p = (const ushort4*)(ybuf + (size_t)rr0 * DD + c);
  const ushort4* y1p = (const ushort4*)(ybuf + (size_t)rr1 * DD + c);
  const ushort4* ysp = (const ushort4*)(ybuf + (size_t)rs * DD + c);
  float4* op = (float4*)(out + (size_t)t * DD + c);
#pragma unroll
  for (int q = 0; q < 2; ++q) {
    ushort4 a = y0p[q], b = y1p[q], s = ysp[q];
    float4 o;
    o.x = w0 * b2f(a.x) + w1 * b2f(b.x) + b2f(s.x);
    o.y = w0 * b2f(a.y) + w1 * b2f(b.y) + b2f(s.y);
    o.z = w0 * b2f(a.z) + w1 * b2f(b.z) + b2f(s.z);
    o.w = w0 * b2f(a.w) + w1 * b2f(b.w) + b2f(s.w);
    op[q] = o;
  }
}

extern "C" void kernel_launch(void* const* d_in, const int* in_sizes, int n_in,
                              void* d_out, int out_size, void* d_ws, size_t ws_size,
                              hipStream_t stream) {
  const float* x   = (const float*)d_in[0];
  const float* gw  = (const float*)d_in[1];
  const float* w1  = (const float*)d_in[2];
  const float* w2  = (const float*)d_in[3];
  const float* w3  = (const float*)d_in[4];
  const float* sw1 = (const float*)d_in[5];
  const float* sw2 = (const float*)d_in[6];
  const float* sw3 = (const float*)d_in[7];
  float* out = (float*)d_out;

  char* ws = (char*)d_ws;
  size_t off = 0;
  int* cnt = (int*)(ws + off);      off += 256;
  int* basep = (int*)(ws + off);    off += 256;
  int* slots = (int*)(ws + off);    off += (size_t)8 * TT * 4;
  int* tok2slot = (int*)(ws + off); off += (size_t)2 * TT * 4;
  float* tok2wgt = (float*)(ws + off); off += (size_t)2 * TT * 4;
  off = (off + 1023) & ~(size_t)1023;
  const size_t WSZ = (size_t)9 * HH * DD;     // elements per weight buffer
  u16* w1b = (u16*)(ws + off);  off += WSZ * 2;
  u16* w3b = (u16*)(ws + off);  off += WSZ * 2;
  u16* w2b = (u16*)(ws + off);  off += WSZ * 2;
  u16* xg  = (u16*)(ws + off);  off += (size_t)3 * TT * DD * 2;  // aliased as ybuf after ffn1
  u16* hbuf = (u16*)(ws + off); off += (size_t)3 * TT * HH * 2;
  u16* ybuf = xg;  // xg dead after ffn1; reuse for ffn2 output

  hipMemsetAsync(cnt, 0, 64, stream);

  const int b = 256;
  int nw = 8 * HH * DD / 4;
  int ns = HH * DD / 4;
  cvt_kernel<<<(nw + b - 1) / b, b, 0, stream>>>(w1, w1b, nw);
  cvt_kernel<<<(ns + b - 1) / b, b, 0, stream>>>(sw1, w1b + (size_t)8 * HH * DD, ns);
  cvt_kernel<<<(nw + b - 1) / b, b, 0, stream>>>(w3, w3b, nw);
  cvt_kernel<<<(ns + b - 1) / b, b, 0, stream>>>(sw3, w3b + (size_t)8 * HH * DD, ns);
  cvt_kernel<<<(nw + b - 1) / b, b, 0, stream>>>(w2, w2b, nw);
  cvt_kernel<<<(ns + b - 1) / b, b, 0, stream>>>(sw2, w2b + (size_t)8 * DD * HH, ns);

  gate_kernel<<<TT, 64, 0, stream>>>(x, gw, cnt, slots, tok2slot, tok2wgt);
  scan_kernel<<<1, 1, 0, stream>>>(cnt, basep);
  gatherx_kernel<<<dim3(TT / 2, 9), 256, 0, stream>>>(x, cnt, basep, slots, xg);

  ffn1_kernel<<<dim3(HH / 128, 64, 9), 256, 0, stream>>>(xg, w1b, w3b, cnt, basep, hbuf);
  ffn2_kernel<<<dim3(DD / 128, 64, 9), 256, 0, stream>>>(hbuf, w2b, cnt, basep, ybuf);
  combine_kernel<<<TT * DD / 8 / 256, 256, 0, stream>>>(ybuf, tok2slot, tok2wgt, basep, out);
}

// Round 3
// 1108.015 us; speedup vs baseline: 1.0963x; 1.0200x over previous
//
#include <hip/hip_runtime.h>

#define TT 8192
#define DD 1024
#define HH 2816
#define NE 8

typedef unsigned short u16;
typedef unsigned int u32;
typedef __attribute__((ext_vector_type(8))) short short8;
typedef __attribute__((ext_vector_type(4))) float floatx4;

__device__ __forceinline__ u16 f2b(float f) {
  unsigned u = __float_as_uint(f);
  unsigned r = u + 0x7fffu + ((u >> 16) & 1u);
  return (u16)(r >> 16);
}
__device__ __forceinline__ float b2f(u16 v) { return __uint_as_float(((u32)v) << 16); }

// async global->LDS, 16B per lane; LDS dest = wave-uniform base + lane*16
__device__ __forceinline__ void gl16(const u16* g, u16* l) {
  __builtin_amdgcn_global_load_lds(
      (const __attribute__((address_space(1))) u32*)g,
      (__attribute__((address_space(3))) u32*)l, 16, 0, 0);
}

// ---------------- fp32 -> bf16 conversion, 3 arrays per launch ----------------
__global__ void cvt3_kernel(const float* __restrict__ s0, const float* __restrict__ s1,
                            const float* __restrict__ s2, u16* __restrict__ d0,
                            u16* __restrict__ d1, u16* __restrict__ d2, int n4) {
  int i = blockIdx.x * blockDim.x + threadIdx.x;
  if (i >= n4) return;
  const float* src = (blockIdx.y == 0) ? s0 : (blockIdx.y == 1) ? s1 : s2;
  u16* dst = (blockIdx.y == 0) ? d0 : (blockIdx.y == 1) ? d1 : d2;
  float4 v = ((const float4*)src)[i];
  ushort4 o;
  o.x = f2b(v.x); o.y = f2b(v.y); o.z = f2b(v.z); o.w = f2b(v.w);
  ((ushort4*)dst)[i] = o;
}

// ---------------- gate ----------------
__global__ void gate_kernel(const float* __restrict__ x, const float* __restrict__ gw,
                            int* __restrict__ cnt, int* __restrict__ slots,
                            int* __restrict__ tok2slot, float* __restrict__ tok2wgt) {
  int t = blockIdx.x;
  int l = threadIdx.x;  // 64 threads = 1 wave
  const float4* xr = (const float4*)(x + (size_t)t * DD);
  float acc[NE];
#pragma unroll
  for (int e = 0; e < NE; ++e) acc[e] = 0.f;
#pragma unroll
  for (int c = 0; c < 4; ++c) {
    float4 xv = xr[l + c * 64];
#pragma unroll
    for (int e = 0; e < NE; ++e) {
      float4 g = ((const float4*)(gw + e * DD))[l + c * 64];
      acc[e] += xv.x * g.x + xv.y * g.y + xv.z * g.z + xv.w * g.w;
    }
  }
#pragma unroll
  for (int e = 0; e < NE; ++e)
    for (int off = 32; off > 0; off >>= 1)
      acc[e] += __shfl_xor(acc[e], off);
  if (l == 0) {
    float m = acc[0];
#pragma unroll
    for (int e = 1; e < NE; ++e) m = fmaxf(m, acc[e]);
    float p[NE]; float s = 0.f;
#pragma unroll
    for (int e = 0; e < NE; ++e) { p[e] = __expf(acc[e] - m); s += p[e]; }
#pragma unroll
    for (int e = 0; e < NE; ++e) p[e] /= s;
    int i1 = 0;
    for (int e = 1; e < NE; ++e) if (p[e] > p[i1]) i1 = e;
    int i2 = (i1 == 0) ? 1 : 0;
    for (int e = 0; e < NE; ++e) if (e != i1 && p[e] > p[i2]) i2 = e;
    float d = p[i1] + p[i2] + 1e-20f;
    float wa = p[i1] / d, wb = p[i2] / d;
    int p1 = atomicAdd(&cnt[i1], 1);
    slots[i1 * TT + p1] = t;
    int p2 = atomicAdd(&cnt[i2], 1);
    slots[i2 * TT + p2] = t;
    tok2slot[2 * t] = i1 * TT + p1;  tok2wgt[2 * t] = wa;
    tok2slot[2 * t + 1] = i2 * TT + p2;  tok2wgt[2 * t + 1] = wb;
  }
}

// ---------------- scan + tilemap (tilemap[i] = e | rt<<8; [255] = ntiles) ----------------
__global__ void scan_kernel(int* __restrict__ cnt, int* __restrict__ basep,
                            int* __restrict__ tilemap) {
  cnt[8] = TT;
  int s = 0, idx = 0;
  for (int e = 0; e < 9; ++e) {
    basep[e] = s;
    int ne = cnt[e];
    int nt = (ne + 127) >> 7;
    for (int rt = 0; rt < nt; ++rt) tilemap[idx++] = e | (rt << 8);
    s += ne;
  }
  basep[9] = s;
  for (int i = idx; i < 255; ++i) tilemap[i] = -1;
  tilemap[255] = idx;  // <= 199 always
}

// ---------------- gather x rows (fp32 -> bf16, compacted; exact 3*TT rows) ----------------
__global__ void gatherx_kernel(const float* __restrict__ x, const int* __restrict__ basep,
                               const int* __restrict__ slots, u16* __restrict__ xg) {
  int r = blockIdx.x * 2 + (threadIdx.x >> 7);  // global compact row in [0, 3*TT)
  int e = 0;
#pragma unroll
  for (int k = 1; k < 9; ++k) e += (r >= basep[k]);
  int p = r - basep[e];
  int tok = (e < 8) ? slots[e * TT + p] : p;
  int lane = threadIdx.x & 127;
  const float4* src = (const float4*)(x + (size_t)tok * DD) + lane * 2;
  float4 v0 = src[0], v1 = src[1];
  ushort4 o0, o1;
  o0.x = f2b(v0.x); o0.y = f2b(v0.y); o0.z = f2b(v0.z); o0.w = f2b(v0.w);
  o1.x = f2b(v1.x); o1.y = f2b(v1.y); o1.z = f2b(v1.z); o1.w = f2b(v1.w);
  ushort4* dp = (ushort4*)(xg + (size_t)r * DD) + lane * 2;
  dp[0] = o0; dp[1] = o1;
}

// ---------------- FFN stage 1: h = silu(xg@w1^T) * (xg@w3^T) ----------------
__global__ __launch_bounds__(256, 2) void ffn1_kernel(
    const u16* __restrict__ xg, const u16* __restrict__ w1b, const u16* __restrict__ w3b,
    const int* __restrict__ cnt, const int* __restrict__ basep,
    const int* __restrict__ tilemap, u16* __restrict__ hbuf) {
  int tm = tilemap[blockIdx.y];
  if (tm < 0) return;
  int e = tm & 255, rt = tm >> 8;
  int ne = (e < 8) ? cnt[e] : TT;
  int c0 = blockIdx.x * 128;
  int tid = threadIdx.x;
  int wv = tid >> 6, l = tid & 63;

  __shared__ u16 sA[128 * 32];
  __shared__ u16 sB1[128 * 32];
  __shared__ u16 sB3[128 * 32];

  int row0 = basep[e] + rt * 128;
  const u16* Ab = xg + (size_t)row0 * DD;
  const u16* B1b = w1b + (size_t)e * HH * DD + (size_t)c0 * DD;
  const u16* B3b = w3b + (size_t)e * HH * DD + (size_t)c0 * DD;

  // staging: granule g (16B) -> LDS slot g; source col XOR-swizzled by row
  int g0 = wv * 64 + l, g1 = 256 + g0;
  int r0 = g0 >> 2, cs0 = ((g0 & 3) ^ ((r0 >> 1) & 3)) * 8;
  int r1 = g1 >> 2, cs1 = ((g1 & 3) ^ ((r1 >> 1) & 3)) * 8;
  const u16* pA0 = Ab + (size_t)r0 * DD + cs0;
  const u16* pA1 = Ab + (size_t)r1 * DD + cs1;
  const u16* pB10 = B1b + (size_t)r0 * DD + cs0;
  const u16* pB11 = B1b + (size_t)r1 * DD + cs1;
  const u16* pB30 = B3b + (size_t)r0 * DD + cs0;
  const u16* pB31 = B3b + (size_t)r1 * DD + cs1;
  u16* dA0 = sA + wv * 512;  u16* dA1 = sA + 2048 + wv * 512;
  u16* dB10 = sB1 + wv * 512; u16* dB11 = sB1 + 2048 + wv * 512;
  u16* dB30 = sB3 + wv * 512; u16* dB31 = sB3 + 2048 + wv * 512;

  int wm = wv & 1, wn = wv >> 1;
  int lo = l & 15, hi = l >> 4;
  int sw8 = (hi ^ ((lo >> 1) & 3)) * 8;
  int aoff = (wm * 64 + lo) * 32 + sw8;
  int boff = (wn * 64 + lo) * 32 + sw8;

  floatx4 acc1[4][4], acc3[4][4];
#pragma unroll
  for (int i = 0; i < 4; ++i)
#pragma unroll
    for (int j = 0; j < 4; ++j) {
      acc1[i][j] = (floatx4){0.f, 0.f, 0.f, 0.f};
      acc3[i][j] = (floatx4){0.f, 0.f, 0.f, 0.f};
    }

  for (int kt = 0; kt < DD / 32; ++kt) {
    gl16(pA0, dA0);  gl16(pA1, dA1);
    gl16(pB10, dB10); gl16(pB11, dB11);
    gl16(pB30, dB30); gl16(pB31, dB31);
    pA0 += 32; pA1 += 32; pB10 += 32; pB11 += 32; pB30 += 32; pB31 += 32;
    __syncthreads();

    short8 af[4], b1f[4], b3f[4];
#pragma unroll
    for (int mi = 0; mi < 4; ++mi)
      af[mi] = *(const short8*)(sA + aoff + mi * 512);
#pragma unroll
    for (int ni = 0; ni < 4; ++ni) {
      b1f[ni] = *(const short8*)(sB1 + boff + ni * 512);
      b3f[ni] = *(const short8*)(sB3 + boff + ni * 512);
    }
#pragma unroll
    for (int mi = 0; mi < 4; ++mi)
#pragma unroll
      for (int ni = 0; ni < 4; ++ni) {
        acc1[mi][ni] = __builtin_amdgcn_mfma_f32_16x16x32_bf16(af[mi], b1f[ni], acc1[mi][ni], 0, 0, 0);
        acc3[mi][ni] = __builtin_amdgcn_mfma_f32_16x16x32_bf16(af[mi], b3f[ni], acc3[mi][ni], 0, 0, 0);
      }
    __syncthreads();
  }

#pragma unroll
  for (int mi = 0; mi < 4; ++mi)
#pragma unroll
    for (int ni = 0; ni < 4; ++ni)
#pragma unroll
      for (int r = 0; r < 4; ++r) {
        int row = wm * 64 + mi * 16 + hi * 4 + r;
        if (rt * 128 + row < ne) {
          int col = c0 + wn * 64 + ni * 16 + lo;
          float v1 = acc1[mi][ni][r], v3 = acc3[mi][ni][r];
          float h = v1 / (1.f + __expf(-v1)) * v3;
          hbuf[(size_t)(row0 + row) * HH + col] = f2b(h);
        }
      }
}

// ---------------- FFN stage 2: y = h @ w2^T (unweighted, bf16) ----------------
__global__ __launch_bounds__(256, 2) void ffn2_kernel(
    const u16* __restrict__ hbuf, const u16* __restrict__ w2b,
    const int* __restrict__ cnt, const int* __restrict__ basep,
    const int* __restrict__ tilemap, u16* __restrict__ ybuf) {
  int tm = tilemap[blockIdx.y];
  if (tm < 0) return;
  int e = tm & 255, rt = tm >> 8;
  int ne = (e < 8) ? cnt[e] : TT;
  int c0 = blockIdx.x * 128;
  int tid = threadIdx.x;
  int wv = tid >> 6, l = tid & 63;

  __shared__ u16 sA[128 * 32];
  __shared__ u16 sB[128 * 32];

  int row0 = basep[e] + rt * 128;
  const u16* Ab = hbuf + (size_t)row0 * HH;
  const u16* Bb = w2b + (size_t)e * DD * HH + (size_t)c0 * HH;

  int g0 = wv * 64 + l, g1 = 256 + g0;
  int r0 = g0 >> 2, cs0 = ((g0 & 3) ^ ((r0 >> 1) & 3)) * 8;
  int r1 = g1 >> 2, cs1 = ((g1 & 3) ^ ((r1 >> 1) & 3)) * 8;
  const u16* pA0 = Ab + (size_t)r0 * HH + cs0;
  const u16* pA1 = Ab + (size_t)r1 * HH + cs1;
  const u16* pB0 = Bb + (size_t)r0 * HH + cs0;
  const u16* pB1 = Bb + (size_t)r1 * HH + cs1;
  u16* dA0 = sA + wv * 512;  u16* dA1 = sA + 2048 + wv * 512;
  u16* dB0 = sB + wv * 512;  u16* dB1 = sB + 2048 + wv * 512;

  int wm = wv & 1, wn = wv >> 1;
  int lo = l & 15, hi = l >> 4;
  int sw8 = (hi ^ ((lo >> 1) & 3)) * 8;
  int aoff = (wm * 64 + lo) * 32 + sw8;
  int boff = (wn * 64 + lo) * 32 + sw8;

  floatx4 acc[4][4];
#pragma unroll
  for (int i = 0; i < 4; ++i)
#pragma unroll
    for (int j = 0; j < 4; ++j) acc[i][j] = (floatx4){0.f, 0.f, 0.f, 0.f};

  for (int kt = 0; kt < HH / 32; ++kt) {
    gl16(pA0, dA0); gl16(pA1, dA1);
    gl16(pB0, dB0); gl16(pB1, dB1);
    pA0 += 32; pA1 += 32; pB0 += 32; pB1 += 32;
    __syncthreads();

    short8 af[4], bf[4];
#pragma unroll
    for (int mi = 0; mi < 4; ++mi)
      af[mi] = *(const short8*)(sA + aoff + mi * 512);
#pragma unroll
    for (int ni = 0; ni < 4; ++ni)
      bf[ni] = *(const short8*)(sB + boff + ni * 512);
#pragma unroll
    for (int mi = 0; mi < 4; ++mi)
#pragma unroll
      for (int ni = 0; ni < 4; ++ni)
        acc[mi][ni] = __builtin_amdgcn_mfma_f32_16x16x32_bf16(af[mi], bf[ni], acc[mi][ni], 0, 0, 0);
    __syncthreads();
  }

#pragma unroll
  for (int mi = 0; mi < 4; ++mi)
#pragma unroll
    for (int ni = 0; ni < 4; ++ni)
#pragma unroll
      for (int r = 0; r < 4; ++r) {
        int row = wm * 64 + mi * 16 + hi * 4 + r;
        if (rt * 128 + row < ne) {
          int col = c0 + wn * 64 + ni * 16 + lo;
          ybuf[(size_t)(row0 + row) * DD + col] = f2b(acc[mi][ni][r]);
        }
      }
}

// ---------------- combine: out[t] = w0*y[s0] + w1*y[s1] + y[shared] ----------------
__global__ void combine_kernel(const u16* __restrict__ ybuf, const int* __restrict__ tok2slot,
                               const float* __restrict__ tok2wgt, const int* __restrict__ basep,
                               float* __restrict__ out) {
  int idx = blockIdx.x * 256 + threadIdx.x;  // TT*DD/8 threads
  int t = idx >> 7;
  int c = (idx & 127) * 8;
  int e0 = tok2slot[2 * t], e1 = tok2slot[2 * t + 1];
  float w0 = tok2wgt[2 * t], w1 = tok2wgt[2 * t + 1];
  int rr0 = basep[e0 >> 13] + (e0 & 8191);
  int rr1 = basep[e1 >> 13] + (e1 & 8191);
  int rs = 2 * TT + t;
  const ushort4* y0p = (const ushort4*)(ybuf + (size_t)rr0 * DD + c);
  const ushort4* y1p = (const ushort4*)(ybuf + (size_t)rr1 * DD + c);
  const ushort4* ysp = (const ushort4*)(ybuf + (size_t)rs * DD + c);
  float4* op = (float4*)(out + (size_t)t * DD + c);
#pragma unroll
  for (int q = 0; q < 2; ++q) {
    ushort4 a = y0p[q], b = y1p[q], s = ysp[q];
    float4 o;
    o.x = w0 * b2f(a.x) + w1 * b2f(b.x) + b2f(s.x);
    o.y = w0 * b2f(a.y) + w1 * b2f(b.y) + b2f(s.y);
    o.z = w0 * b2f(a.z) + w1 * b2f(b.z) + b2f(s.z);
    o.w = w0 * b2f(a.w) + w1 * b2f(b.w) + b2f(s.w);
    op[q] = o;
  }
}

extern "C" void kernel_launch(void* const* d_in, const int* in_sizes, int n_in,
                              void* d_out, int out_size, void* d_ws, size_t ws_size,
                              hipStream_t stream) {
  const float* x   = (const float*)d_in[0];
  const float* gw  = (const float*)d_in[1];
  const float* w1  = (const float*)d_in[2];
  const float* w2  = (const float*)d_in[3];
  const float* w3  = (const float*)d_in[4];
  const float* sw1 = (const float*)d_in[5];
  const float* sw2 = (const float*)d_in[6];
  const float* sw3 = (const float*)d_in[7];
  float* out = (float*)d_out;

  char* ws = (char*)d_ws;
  size_t off = 0;
  int* cnt = (int*)(ws + off);      off += 256;
  int* basep = (int*)(ws + off);    off += 256;
  int* tilemap = (int*)(ws + off);  off += 1024;
  int* slots = (int*)(ws + off);    off += (size_t)8 * TT * 4;
  int* tok2slot = (int*)(ws + off); off += (size_t)2 * TT * 4;
  float* tok2wgt = (float*)(ws + off); off += (size_t)2 * TT * 4;
  off = (off + 1023) & ~(size_t)1023;
  const size_t WSZ = (size_t)9 * HH * DD;     // elements per weight buffer
  u16* w1b = (u16*)(ws + off);  off += WSZ * 2;
  u16* w3b = (u16*)(ws + off);  off += WSZ * 2;
  u16* w2b = (u16*)(ws + off);  off += WSZ * 2;
  u16* xg  = (u16*)(ws + off);  off += (size_t)3 * TT * DD * 2;  // aliased as ybuf after ffn1
  u16* hbuf = (u16*)(ws + off); off += (size_t)3 * TT * HH * 2;
  u16* ybuf = xg;  // xg dead after ffn1; reuse for ffn2 output

  hipMemsetAsync(cnt, 0, 64, stream);

  const int b = 256;
  int nw = 8 * HH * DD / 4;   // 5,767,168 float4 groups
  int ns = HH * DD / 4;       //   720,896
  cvt3_kernel<<<dim3((nw + b - 1) / b, 3), b, 0, stream>>>(
      w1, w3, w2, w1b, w3b, w2b, nw);
  cvt3_kernel<<<dim3((ns + b - 1) / b, 3), b, 0, stream>>>(
      sw1, sw3, sw2,
      w1b + (size_t)8 * HH * DD, w3b + (size_t)8 * HH * DD, w2b + (size_t)8 * DD * HH, ns);

  gate_kernel<<<TT, 64, 0, stream>>>(x, gw, cnt, slots, tok2slot, tok2wgt);
  scan_kernel<<<1, 1, 0, stream>>>(cnt, basep, tilemap);
  gatherx_kernel<<<3 * TT / 2, 256, 0, stream>>>(x, basep, slots, xg);

  ffn1_kernel<<<dim3(HH / 128, 200), 256, 0, stream>>>(xg, w1b, w3b, cnt, basep, tilemap, hbuf);
  ffn2_kernel<<<dim3(DD / 128, 200), 256, 0, stream>>>(hbuf, w2b, cnt, basep, tilemap, ybuf);
  combine_kernel<<<TT * DD / 8 / 256, 256, 0, stream>>>(ybuf, tok2slot, tok2wgt, basep, out);
}